// Round 1
// baseline (614.513 us; speedup 1.0000x reference)
//
#include <hip/hip_runtime.h>

#define D_MODEL 2048
#define D_INNER 4096
#define D_STATE 128
#define HEADDIM 64
#define NHEADS 64
#define CONV_DIM 4352
#define D_IN_PROJ 8512
#define BB 2
#define TSEQ 2048
#define BT (BB*TSEQ)
#define NCHUNK 32
#define LCH 64
#define EPS_F 1e-5f

typedef __bf16 bf16x8 __attribute__((ext_vector_type(8)));
typedef float f32x4 __attribute__((ext_vector_type(4)));

__device__ __forceinline__ float bf2f(unsigned short u){
  unsigned int x = ((unsigned int)u) << 16;
  return __builtin_bit_cast(float, x);
}
__device__ __forceinline__ unsigned short f2bf(float f){
  unsigned int x = __builtin_bit_cast(unsigned int, f);
  x += 0x7fffu + ((x >> 16) & 1u);
  return (unsigned short)(x >> 16);
}

// async global->LDS, 16 B/lane: LDS dest = wave-uniform base + lane*16.
__device__ __forceinline__ void async_copy16(const unsigned short* g, unsigned short* l) {
  __builtin_amdgcn_global_load_lds(
      (const __attribute__((address_space(1))) unsigned int*)g,
      (__attribute__((address_space(3))) unsigned int*)l, 16, 0, 0);
}

// fp32 -> bf16 cast, 8 elems/thread. n % 8 == 0.
__global__ __launch_bounds__(256) void cast_kernel(
    const float* __restrict__ in, unsigned short* __restrict__ out, int n)
{
  int i = (blockIdx.x * 256 + threadIdx.x) * 8;
  if (i >= n) return;
  float4 a = *(const float4*)&in[i];
  float4 b = *(const float4*)&in[i + 4];
  unsigned short o[8] = { f2bf(a.x), f2bf(a.y), f2bf(a.z), f2bf(a.w),
                          f2bf(b.x), f2bf(b.y), f2bf(b.z), f2bf(b.w) };
  *(uint4*)&out[i] = *(uint4*)o;
}

// ---------------------------------------------------------------------------
// 256x256-tile GEMM, deep-pipelined (T3+T4+T5 structure).
// C[m,n] = sum_k A[m,k]*B[n,k].  8 waves (2M x 4N), per-wave out 128x64.
// K in 32-wide units; LDS = 4-slot ring per operand (slot 256x32 bf16, 16KB),
// staging 3 units ahead via global_load_lds; ONE counted s_waitcnt vmcnt(8)
// + barrier per unit (never drain to 0 in steady state); setprio around MFMA.
// Ledger (per wave, 4 loads/unit, FIFO): at start of unit u the outstanding
// loads are units u,u+1,u+2 (=12) -> vmcnt(8) retires exactly unit u.
// Slot (u+3)&3 staged during u was last READ by unit u-1; the start-of-u
// barrier separates those reads from the staging issues. Tail: vmcnt(4)/0.
// Swizzle: LDS(r,b) = global(r, b^(r&3)) via pre-swizzled source; read with
// the same XOR (rule #21 both-sides). Uniform 8 lanes per 4-bank cluster on
// ds_read_b128 (same family as the 128^2 kernel that measures 0 conflicts).
// N may exceed real columns (padded NT): stores guarded col<N; garbage B rows
// only feed accumulator lanes whose columns are >= N (never stored).
// ---------------------------------------------------------------------------
template <bool F32OUT>
__global__ __launch_bounds__(512, 2) void gemm256_kernel(
    const unsigned short* __restrict__ A, const unsigned short* __restrict__ Bm,
    void* __restrict__ Cout, int M, int N, int K, int NT, int MT)
{
  __shared__ __align__(16) unsigned short As[4][256 * 32];
  __shared__ __align__(16) unsigned short Bs[4][256 * 32];
  int tid = threadIdx.x;

  // band-swizzled grid (8-wide nt bands) for L2 locality
  int bid = blockIdx.x;
  int fullBands = NT >> 3;
  int blocksFull = fullBands * 8 * MT;
  int mt, nt;
  if (bid < blocksFull) {
    int band = bid / (8 * MT);
    int wI = bid - band * (8 * MT);
    nt = band * 8 + (wI & 7);
    mt = wI >> 3;
  } else {
    int rem = bid - blocksFull;
    int WL = NT - fullBands * 8;
    nt = fullBands * 8 + rem % WL;
    mt = rem / WL;
  }
  int m0 = mt * 256, n0 = nt * 256;

  int wid = tid >> 6, lane = tid & 63;
  int wm = wid >> 2, wn = wid & 3;              // wave tile: rows wm*128, cols wn*64
  int lm = lane & 15, kqb = lane >> 4;
  int rsw = (kqb ^ (lm & 3)) * 8;               // swizzled in-row short offset

  // staging: thread covers (row=tid>>2, blk=tid&3) of a 128-row x 32-col issue;
  // source block pre-swizzled so LDS stays linear (wave-uniform dest + lane*16).
  int srow = tid >> 2;
  int sblk = (tid & 3) ^ (srow & 3);
  const unsigned short* Ap = A + (size_t)(m0 + srow) * K + sblk * 8;
  const unsigned short* Bp = Bm + (size_t)(n0 + srow) * K + sblk * 8;

  f32x4 acc[8][4] = {};
  const int U = K >> 5;                         // 32-wide K units

  // prologue: issue units 0,1,2 (12 loads/wave in flight)
#pragma unroll
  for (int u = 0; u < 3; u++) {
    int ku = u << 5;
    async_copy16(Ap + ku, &As[u][wid * 512]);
    async_copy16(Ap + (size_t)128 * K + ku, &As[u][4096 + wid * 512]);
    async_copy16(Bp + ku, &Bs[u][wid * 512]);
    async_copy16(Bp + (size_t)128 * K + ku, &Bs[u][4096 + wid * 512]);
  }

  for (int u = 0; u < U; u++) {
    int s = u & 3;
    int left = U - 1 - u;
    if (left >= 2)      asm volatile("s_waitcnt vmcnt(8)" ::: "memory");
    else if (left == 1) asm volatile("s_waitcnt vmcnt(4)" ::: "memory");
    else                asm volatile("s_waitcnt vmcnt(0)" ::: "memory");
    __builtin_amdgcn_s_barrier();

    const unsigned short* Ab = &As[s][wm * 4096];
    const unsigned short* Bb = &Bs[s][(wn * 64) * 32];
    int up = u + 3;
    int kup = up << 5, sp = up & 3;

    // ---- phase 0: B frags (reused both phases) + A frags 0-3; stage A(u+3)
    bf16x8 bfr[4], af[4];
#pragma unroll
    for (int j = 0; j < 4; j++) bfr[j] = *(const bf16x8*)&Bb[(j * 16 + lm) * 32 + rsw];
#pragma unroll
    for (int i = 0; i < 4; i++) af[i] = *(const bf16x8*)&Ab[(i * 16 + lm) * 32 + rsw];
    if (up < U) {
      async_copy16(Ap + kup, &As[sp][wid * 512]);
      async_copy16(Ap + (size_t)128 * K + kup, &As[sp][4096 + wid * 512]);
    }
    __builtin_amdgcn_s_setprio(1);
#pragma unroll
    for (int i = 0; i < 4; i++)
#pragma unroll
      for (int j = 0; j < 4; j++)
        acc[i][j] = __builtin_amdgcn_mfma_f32_16x16x32_bf16(af[i], bfr[j], acc[i][j], 0, 0, 0);
    __builtin_amdgcn_s_setprio(0);
    __builtin_amdgcn_s_barrier();

    // ---- phase 1: A frags 4-7; stage B(u+3)
#pragma unroll
    for (int i = 0; i < 4; i++) af[i] = *(const bf16x8*)&Ab[((4 + i) * 16 + lm) * 32 + rsw];
    if (up < U) {
      async_copy16(Bp + kup, &Bs[sp][wid * 512]);
      async_copy16(Bp + (size_t)128 * K + kup, &Bs[sp][4096 + wid * 512]);
    }
    __builtin_amdgcn_s_setprio(1);
#pragma unroll
    for (int i = 0; i < 4; i++)
#pragma unroll
      for (int j = 0; j < 4; j++)
        acc[4 + i][j] = __builtin_amdgcn_mfma_f32_16x16x32_bf16(af[i], bfr[j], acc[4 + i][j], 0, 0, 0);
    __builtin_amdgcn_s_setprio(0);
    // no bottom barrier: next unit's vmcnt+barrier provides the separation
  }

  int rq = lane >> 4;
#pragma unroll
  for (int i = 0; i < 8; i++) {
#pragma unroll
    for (int j = 0; j < 4; j++) {
      int col = n0 + wn * 64 + j * 16 + lm;
      if (col < N) {
        int mrow = m0 + wm * 128 + i * 16 + rq * 4;
#pragma unroll
        for (int r = 0; r < 4; r++) {
          if (F32OUT) ((float*)Cout)[(size_t)(mrow + r) * N + col] = acc[i][j][r];
          else ((unsigned short*)Cout)[(size_t)(mrow + r) * N + col] = f2bf(acc[i][j][r]);
        }
      }
    }
  }
}

// C[m,n] = sum_k A[m,k]*B[n,k]; m97-style staging, XOR-8 LDS swizzle,
// band-swizzled grid. Kept for GEMM2 (N=2048: 256^2 tiles would leave
// half the CUs idle at 128 workgroups).
template <bool F32OUT>
__global__ __launch_bounds__(256) void gemm_tn_kernel(
    const unsigned short* __restrict__ A, const unsigned short* __restrict__ Bm,
    void* __restrict__ Cout, int M, int N, int K, int NT, int MT)
{
  __shared__ __align__(16) unsigned short As[128 * 64];
  __shared__ __align__(16) unsigned short Bs[128 * 64];
  int tid = threadIdx.x;

  int bid = blockIdx.x;
  int fullBands = NT >> 3;
  int blocksFull = fullBands * 8 * MT;
  int mt, nt;
  if (bid < blocksFull) {
    int band = bid / (8 * MT);
    int wI = bid - band * (8 * MT);
    nt = band * 8 + (wI & 7);
    mt = wI >> 3;
  } else {
    int rem = bid - blocksFull;
    int WL = NT - fullBands * 8;
    nt = fullBands * 8 + rem % WL;
    mt = rem / WL;
  }
  int m0 = mt * 128, n0 = nt * 128;

  int wave = tid >> 6, lane = tid & 63;
  int wm = wave >> 1, wn = wave & 1;
  int lm = lane & 15, kqb = lane >> 4;
  int sw = lm & 7;

  int lr = lane >> 3, lc = lane & 7, bg = lc ^ lr;
  const unsigned short* Ap = A + (size_t)(m0 + wave * 32 + lr) * K + bg * 8;
  const unsigned short* Bp = Bm + (size_t)(n0 + wave * 32 + lr) * K + bg * 8;

  f32x4 acc[4][4] = {};

  for (int k0 = 0; k0 < K; k0 += 64) {
#pragma unroll
    for (int q = 0; q < 4; q++) {
      async_copy16(Ap + (size_t)q * 8 * K + k0, &As[(wave * 32 + q * 8) * 64]);
      async_copy16(Bp + (size_t)q * 8 * K + k0, &Bs[(wave * 32 + q * 8) * 64]);
    }
    __syncthreads();
#pragma unroll
    for (int kk = 0; kk < 64; kk += 32) {
      int b0 = (kk >> 3) + kqb;
      int boff = (b0 ^ sw) * 8;
      bf16x8 af[4], bfr[4];
#pragma unroll
      for (int i = 0; i < 4; i++) af[i]  = *(const bf16x8*)&As[(wm * 64 + i * 16 + lm) * 64 + boff];
#pragma unroll
      for (int j = 0; j < 4; j++) bfr[j] = *(const bf16x8*)&Bs[(wn * 64 + j * 16 + lm) * 64 + boff];
#pragma unroll
      for (int i = 0; i < 4; i++)
#pragma unroll
        for (int j = 0; j < 4; j++)
          acc[i][j] = __builtin_amdgcn_mfma_f32_16x16x32_bf16(af[i], bfr[j], acc[i][j], 0, 0, 0);
    }
    __syncthreads();
  }

  int rq = lane >> 4;
#pragma unroll
  for (int i = 0; i < 4; i++) {
#pragma unroll
    for (int j = 0; j < 4; j++) {
      int col = n0 + wn * 64 + j * 16 + lm;
      if (col < N) {
        int mrow = m0 + wm * 64 + i * 16 + rq * 4;
#pragma unroll
        for (int r = 0; r < 4; r++) {
          if (F32OUT) ((float*)Cout)[(size_t)(mrow + r) * N + col] = acc[i][j][r];
          else ((unsigned short*)Cout)[(size_t)(mrow + r) * N + col] = f2bf(acc[i][j][r]);
        }
      }
    }
  }
}

// Depthwise causal conv (window 4) + bias + silu. B/C now stored bf16.
__global__ __launch_bounds__(256) void conv_silu_kernel(
    const unsigned short* __restrict__ zx, const float* __restrict__ conv_w,
    const float* __restrict__ conv_b, unsigned short* __restrict__ xconv,
    unsigned short* __restrict__ Bbf, unsigned short* __restrict__ Cbf)
{
  const int NG = CONV_DIM / 8;
  int gid = blockIdx.x * 256 + threadIdx.x;
  if (gid >= BT * NG) return;
  int cg = gid % NG; int bt = gid / NG;
  int t = bt % TSEQ;
  int c0 = cg * 8;

  float wgt[8][4];
#pragma unroll
  for (int i = 0; i < 8; i++)
#pragma unroll
    for (int k = 0; k < 4; k++) wgt[i][k] = conv_w[(c0 + i) * 4 + k];

  float acc[8];
#pragma unroll
  for (int i = 0; i < 8; i++) acc[i] = conv_b[c0 + i];

#pragma unroll
  for (int k = 0; k < 4; k++) {
    int ts = t - 3 + k;
    if (ts < 0) continue;
    unsigned short xv[8];
    *(uint4*)xv = *(const uint4*)&zx[(size_t)(bt - 3 + k) * D_IN_PROJ + D_INNER + c0];
#pragma unroll
    for (int i = 0; i < 8; i++) acc[i] = fmaf(bf2f(xv[i]), wgt[i][k], acc[i]);
  }

  unsigned short o[8];
#pragma unroll
  for (int i = 0; i < 8; i++) { float v = acc[i]; o[i] = f2bf(v / (1.f + expf(-v))); }
  if (c0 < D_INNER) {
    *(uint4*)&xconv[(size_t)bt * D_INNER + c0] = *(uint4*)o;
  } else if (c0 < D_INNER + D_STATE) {
    *(uint4*)&Bbf[(size_t)bt * D_STATE + (c0 - D_INNER)] = *(uint4*)o;
  } else {
    *(uint4*)&Cbf[(size_t)bt * D_STATE + (c0 - D_INNER - D_STATE)] = *(uint4*)o;
  }
}

// Fused: dt = softplus(dt_raw + bias); la = dt*A; per-chunk inclusive cumsum.
// One wave per (cb,h); lane = t within chunk.
__global__ __launch_bounds__(256) void dtcum_kernel(
    const unsigned short* __restrict__ zx, const float* __restrict__ dt_bias,
    const float* __restrict__ A_log, float* __restrict__ dtv, float* __restrict__ ca)
{
  int g = blockIdx.x * 4 + (threadIdx.x >> 6);   // g = cb*64 + h
  int lane = threadIdx.x & 63;
  int h = g & 63; int cb = g >> 6;
  size_t bt = (size_t)cb * 64 + lane;
  float xr = bf2f(zx[bt * D_IN_PROJ + D_INNER + CONV_DIM + h]) + dt_bias[h];
  float dt = (xr > 20.f) ? xr : log1pf(expf(xr));
  float v = dt * (-expf(A_log[h]));
#pragma unroll
  for (int off = 1; off < 64; off <<= 1) {
    float t = __shfl_up(v, off);
    if (lane >= off) v += t;
  }
  dtv[bt * NHEADS + h] = dt;
  ca[(size_t)g * 64 + lane] = v;
}

// G[i,j] = sum_n C[i,n]*B[j,n] per (b,chunk). Shared across heads (NGROUPS=1).
__global__ __launch_bounds__(256) void chunk_g_kernel(
    const unsigned short* __restrict__ Bbf, const unsigned short* __restrict__ Cbf,
    unsigned short* __restrict__ G)
{
  __shared__ __align__(16) unsigned short Cs[64][136];
  __shared__ __align__(16) unsigned short Bs2[64][136];
  int tid = threadIdx.x; int cb = blockIdx.x;
  size_t bt0 = (size_t)cb * 64;
  int row = tid >> 2, seg = (tid & 3) * 32;
#pragma unroll
  for (int u = 0; u < 32; u += 8) {
    *(uint4*)&Cs[row][seg + u]  = *(const uint4*)&Cbf[(bt0 + row) * 128 + seg + u];
    *(uint4*)&Bs2[row][seg + u] = *(const uint4*)&Bbf[(bt0 + row) * 128 + seg + u];
  }
  __syncthreads();
  int wave = tid >> 6, lane = tid & 63, lm = lane & 15, kq = (lane >> 4) * 8, rq = lane >> 4;
  f32x4 acc[4] = {};
#pragma unroll
  for (int ks = 0; ks < 4; ks++) {
    bf16x8 af = *(const bf16x8*)&Cs[wave * 16 + lm][ks * 32 + kq];
#pragma unroll
    for (int jt = 0; jt < 4; jt++) {
      bf16x8 bb = *(const bf16x8*)&Bs2[jt * 16 + lm][ks * 32 + kq];
      acc[jt] = __builtin_amdgcn_mfma_f32_16x16x32_bf16(af, bb, acc[jt], 0, 0, 0);
    }
  }
#pragma unroll
  for (int jt = 0; jt < 4; jt++)
#pragma unroll
    for (int r = 0; r < 4; r++) {
      int i = wave * 16 + rq * 4 + r, j = jt * 16 + lm;
      G[(size_t)cb * 4096 + i * 64 + j] = f2bf(acc[jt][r]);
    }
}

// S[p,n] = sum_j exp(ca63-ca[j])*dt[j]*x[j,p] * B[j,n]. 4 heads per block:
// Bn (shared across heads) staged once; Ax restaged per head.
__global__ __launch_bounds__(256) void chunk_state_kernel(
    const unsigned short* __restrict__ Bbf, const unsigned short* __restrict__ xconv,
    const float* __restrict__ dtv, const float* __restrict__ ca,
    unsigned short* __restrict__ S)
{
  __shared__ __align__(16) unsigned short Ax[64][72];
  __shared__ __align__(16) unsigned short Bn[128][72];
  int tid = threadIdx.x;
  int c = blockIdx.x & 31, hb = (blockIdx.x >> 5) & 15, b = blockIdx.x >> 9;
  int cb = b * 32 + c;
  size_t bt0 = (size_t)cb * 64;
  {
    int j = tid >> 2, nseg = (tid & 3) * 32;
    unsigned short bv[32];
#pragma unroll
    for (int u = 0; u < 32; u += 8)
      *(uint4*)&bv[u] = *(const uint4*)&Bbf[(bt0 + j) * 128 + nseg + u];
#pragma unroll
    for (int u = 0; u < 32; u++) Bn[nseg + u][j] = bv[u];
  }
  int wave = tid >> 6, lane = tid & 63, lm = lane & 15, kq = (lane >> 4) * 8, rq = lane >> 4;
  int j = tid >> 2, pseg = (tid & 3) * 16;
  for (int hh = 0; hh < 4; hh++) {
    int h = hb * 4 + hh;
    const float* cag = &ca[((size_t)cb * 64 + h) * 64];
    float wj = expf(cag[63] - cag[j]) * dtv[(bt0 + j) * 64 + h];
    unsigned short xv[16];
    *(uint4*)&xv[0] = *(const uint4*)&xconv[(bt0 + j) * 4096 + h * 64 + pseg];
    *(uint4*)&xv[8] = *(const uint4*)&xconv[(bt0 + j) * 4096 + h * 64 + pseg + 8];
    if (hh) __syncthreads();           // prior iteration's reads complete
#pragma unroll
    for (int q = 0; q < 16; q++) Ax[pseg + q][j] = f2bf(wj * bf2f(xv[q]));
    __syncthreads();
    f32x4 acc[8] = {};
#pragma unroll
    for (int ks = 0; ks < 2; ks++) {
      bf16x8 af = *(const bf16x8*)&Ax[wave * 16 + lm][ks * 32 + kq];
#pragma unroll
      for (int nt = 0; nt < 8; nt++) {
        bf16x8 bb = *(const bf16x8*)&Bn[nt * 16 + lm][ks * 32 + kq];
        acc[nt] = __builtin_amdgcn_mfma_f32_16x16x32_bf16(af, bb, acc[nt], 0, 0, 0);
      }
    }
    size_t sbase = ((size_t)(b * 64 + h) * 32 + c) * 8192;
#pragma unroll
    for (int nt = 0; nt < 8; nt++)
#pragma unroll
      for (int r = 0; r < 4; r++) {
        int p = wave * 16 + rq * 4 + r, n = nt * 16 + lm;
        S[sbase + p * 128 + n] = f2bf(acc[nt][r]);
      }
  }
}

// Sequential pass over 32 chunks: read S[c], write h_in[c] in place,
// h = exp(ca63_c)*h + S[c]. Per (b,h); thread owns 4 state elems.
__global__ __launch_bounds__(256) void state_pass_kernel(
    unsigned short* __restrict__ Shin, const float* __restrict__ ca)
{
  int part = blockIdx.x & 7, bh = blockIdx.x >> 3;
  int h = bh & 63, b = bh >> 6;
  int e0 = part * 1024 + threadIdx.x * 4;
  size_t base = (size_t)bh * 32 * 8192;
  float hc[4] = {0.f, 0.f, 0.f, 0.f};
  for (int c = 0; c < 32; c++) {
    float sc = expf(ca[(((size_t)(b * 32 + c)) * 64 + h) * 64 + 63]);
    size_t off = base + (size_t)c * 8192 + e0;
    uint2 sv = *(uint2*)&Shin[off];
    unsigned short* sp = (unsigned short*)&sv;
    unsigned short ho[4];
#pragma unroll
    for (int q = 0; q < 4; q++) ho[q] = f2bf(hc[q]);
    *(uint2*)&Shin[off] = *(uint2*)ho;
#pragma unroll
    for (int q = 0; q < 4; q++) hc[q] = sc * hc[q] + bf2f(sp[q]);
  }
}

// y[i,p] = sum_j M'[i,j]*x[j,p] + sum_n (C[i,n]e^ca_i)*hin[p,n] + Dskip*x[i,p]
// with dt folded into M' = G*exp(ca_i-ca_j)*dt_j. One K=192 MFMA per (b,h,c).
__global__ __launch_bounds__(256) void chunk_y_kernel(
    const unsigned short* __restrict__ G, const unsigned short* __restrict__ Cbf,
    const unsigned short* __restrict__ xconv, const float* __restrict__ dtv,
    const float* __restrict__ ca, const unsigned short* __restrict__ hin,
    const float* __restrict__ Dskip, unsigned short* __restrict__ yp)
{
  __shared__ __align__(16) unsigned short Aop[64][200];
  __shared__ __align__(16) unsigned short Bop[64][200];
  __shared__ float cas[64]; __shared__ float dts[64];
  int tid = threadIdx.x;
  int c = blockIdx.x & 31, h = (blockIdx.x >> 5) & 63, b = blockIdx.x >> 11;
  int cb = b * 32 + c;
  size_t bt0 = (size_t)cb * 64;
  if (tid < 64) {
    cas[tid] = ca[((size_t)cb * 64 + h) * 64 + tid];
    dts[tid] = dtv[(bt0 + tid) * 64 + h];
  }
  __syncthreads();
  {
    int i = tid >> 2, jseg = (tid & 3) * 16;
    float cai = cas[i];
    unsigned short gv[16];
    *(uint4*)&gv[0] = *(const uint4*)&G[(size_t)cb * 4096 + i * 64 + jseg];
    *(uint4*)&gv[8] = *(const uint4*)&G[(size_t)cb * 4096 + i * 64 + jseg + 8];
    unsigned short o[16];
#pragma unroll
    for (int q = 0; q < 16; q++) {
      int j = jseg + q;
      float m = (j <= i) ? bf2f(gv[q]) * expf(cai - cas[j]) * dts[j] : 0.f;
      o[q] = f2bf(m);
    }
    *(uint4*)&Aop[i][jseg] = *(uint4*)&o[0];
    *(uint4*)&Aop[i][jseg + 8] = *(uint4*)&o[8];
  }
  {
    int i = tid >> 2, nseg = (tid & 3) * 32;
    float sci = expf(cas[i]);
#pragma unroll
    for (int u = 0; u < 32; u += 8) {
      unsigned short cv[8];
      *(uint4*)cv = *(const uint4*)&Cbf[(bt0 + i) * 128 + nseg + u];
      unsigned short o[8];
#pragma unroll
      for (int q = 0; q < 8; q++) o[q] = f2bf(sci * bf2f(cv[q]));
      *(uint4*)&Aop[i][64 + nseg + u] = *(uint4*)o;
    }
  }
  {
    int j = tid >> 2, pseg = (tid & 3) * 16;
    unsigned short xv[16];
    *(uint4*)&xv[0] = *(const uint4*)&xconv[(bt0 + j) * 4096 + h * 64 + pseg];
    *(uint4*)&xv[8] = *(const uint4*)&xconv[(bt0 + j) * 4096 + h * 64 + pseg + 8];
#pragma unroll
    for (int q = 0; q < 16; q++) Bop[pseg + q][j] = xv[q];
  }
  {
    int p = tid >> 2, nseg = (tid & 3) * 32;
    size_t hb = ((size_t)(b * 64 + h) * 32 + c) * 8192 + p * 128 + nseg;
#pragma unroll
    for (int u = 0; u < 32; u += 8)
      *(uint4*)&Bop[p][64 + nseg + u] = *(const uint4*)&hin[hb + u];
  }
  __syncthreads();
  int wave = tid >> 6, lane = tid & 63, lm = lane & 15, kq = (lane >> 4) * 8, rq = lane >> 4;
  f32x4 acc[4] = {};
#pragma unroll
  for (int ks = 0; ks < 6; ks++) {
    bf16x8 af = *(const bf16x8*)&Aop[wave * 16 + lm][ks * 32 + kq];
#pragma unroll
    for (int pt = 0; pt < 4; pt++) {
      bf16x8 bb = *(const bf16x8*)&Bop[pt * 16 + lm][ks * 32 + kq];
      acc[pt] = __builtin_amdgcn_mfma_f32_16x16x32_bf16(af, bb, acc[pt], 0, 0, 0);
    }
  }
  float dsk = Dskip[h];
#pragma unroll
  for (int pt = 0; pt < 4; pt++)
#pragma unroll
    for (int r = 0; r < 4; r++) {
      int i = wave * 16 + rq * 4 + r, p = pt * 16 + lm;
      float y = acc[pt][r] + dsk * bf2f(Bop[p][i]);   // Bop[p][i] = x[i,p]
      yp[(bt0 + i) * 4096 + h * 64 + p] = f2bf(y);
    }
}

// gate with silu(z), rmsnorm, write bf16.
__global__ __launch_bounds__(256) void gate_norm_kernel(
    const unsigned short* __restrict__ yp, const unsigned short* __restrict__ zx,
    const float* __restrict__ norm_w, unsigned short* __restrict__ ybf)
{
  int row = blockIdx.x; int tid = threadIdx.x;
  int c0 = tid * 16;
  unsigned short y0[16], zv[16];
  const size_t base = (size_t)row * D_INNER + c0;
  *(uint4*)&y0[0] = *(const uint4*)&yp[base];
  *(uint4*)&y0[8] = *(const uint4*)&yp[base + 8];
  const size_t zbase = (size_t)row * D_IN_PROJ + c0;
  *(uint4*)&zv[0] = *(const uint4*)&zx[zbase];
  *(uint4*)&zv[8] = *(const uint4*)&zx[zbase + 8];

  float g[16]; float ss = 0.f;
#pragma unroll
  for (int i = 0; i < 16; i++) {
    float y = bf2f(y0[i]);
    float z = bf2f(zv[i]);
    float gate = z / (1.f + expf(-z));
    float gv = y * gate;
    g[i] = gv; ss += gv * gv;
  }
#pragma unroll
  for (int o = 32; o >= 1; o >>= 1) ss += __shfl_xor(ss, o);
  __shared__ float red[4]; __shared__ float stot;
  if ((tid & 63) == 0) red[tid >> 6] = ss;
  __syncthreads();
  if (tid == 0) stot = red[0] + red[1] + red[2] + red[3];
  __syncthreads();
  float scale = rsqrtf(stot * (1.f / D_INNER) + EPS_F);
  unsigned short o16[16];
#pragma unroll
  for (int i = 0; i < 16; i++) o16[i] = f2bf(g[i] * scale * norm_w[c0 + i]);
  *(uint4*)&ybf[base] = *(uint4*)&o16[0];
  *(uint4*)&ybf[base + 8] = *(uint4*)&o16[8];
}

extern "C" void kernel_launch(void* const* d_in, const int* in_sizes, int n_in,
                              void* d_out, int out_size, void* d_ws, size_t ws_size,
                              hipStream_t stream) {
  (void)in_sizes; (void)n_in; (void)out_size; (void)ws_size;
  const float* x          = (const float*)d_in[0];
  const float* in_proj_w  = (const float*)d_in[3];
  const float* conv_w     = (const float*)d_in[4];
  const float* conv_b     = (const float*)d_in[5];
  const float* dt_bias    = (const float*)d_in[6];
  const float* A_log      = (const float*)d_in[7];
  const float* Dskip      = (const float*)d_in[8];
  const float* norm_w     = (const float*)d_in[9];
  const float* out_proj_w = (const float*)d_in[10];
  float* out = (float*)d_out;

  char* w = (char*)d_ws;
  unsigned short* zx    = (unsigned short*)(w);
  unsigned short* xconv = (unsigned short*)(w + 69730304);
  unsigned short* Bbf = (unsigned short*)(w + 103284736);   // BT*128 bf16
  unsigned short* Cbf = (unsigned short*)(w + 105381888);   // BT*128 bf16
  float* dtv = (float*)(w + 107479040);
  float* ca  = (float*)(w + 109576192);
  unsigned short* G    = (unsigned short*)(w + 110624768);
  unsigned short* Shin = (unsigned short*)(w + 111149056);
  unsigned short* yp   = (unsigned short*)(w + 178257920);
  unsigned short* xb   = (unsigned short*)(w + 111149056);   // pre-scan overlay
  unsigned short* wib  = (unsigned short*)(w + 127926272);   // pre-scan overlay (padded to 8704 rows)
  unsigned short* ybf  = (unsigned short*)(w + 111149056);   // post-scan overlay
  unsigned short* wob  = (unsigned short*)(w + 144703488);   // post-scan overlay

  cast_kernel<<<BT * D_MODEL / 8 / 256, 256, 0, stream>>>(x, xb, BT * D_MODEL);
  cast_kernel<<<D_IN_PROJ * D_MODEL / 8 / 256, 256, 0, stream>>>(in_proj_w, wib, D_IN_PROJ * D_MODEL);
  {
    // 256^2 deep-pipelined GEMM; N padded to 34 tiles (8704). Rows 8512..8703
    // of wib are garbage: they feed only accumulator columns >= N (store-guarded).
    int NT = 34, MT = BT / 256;
    gemm256_kernel<false><<<NT * MT, 512, 0, stream>>>(
        xb, wib, zx, BT, D_IN_PROJ, D_MODEL, NT, MT);
  }
  conv_silu_kernel<<<(BT * (CONV_DIM / 8) + 255) / 256, 256, 0, stream>>>(
      zx, conv_w, conv_b, xconv, Bbf, Cbf);
  dtcum_kernel<<<BB * NCHUNK * NHEADS / 4, 256, 0, stream>>>(zx, dt_bias, A_log, dtv, ca);
  chunk_g_kernel<<<BB * NCHUNK, 256, 0, stream>>>(Bbf, Cbf, G);
  chunk_state_kernel<<<BB * 16 * NCHUNK, 256, 0, stream>>>(Bbf, xconv, dtv, ca, Shin);
  state_pass_kernel<<<BB * NHEADS * 8, 256, 0, stream>>>(Shin, ca);
  chunk_y_kernel<<<BB * NHEADS * NCHUNK, 256, 0, stream>>>(G, Cbf, xconv, dtv, ca, Shin, Dskip, yp);
  gate_norm_kernel<<<BT, 256, 0, stream>>>(yp, zx, norm_w, ybf);
  cast_kernel<<<D_MODEL * D_INNER / 8 / 256, 256, 0, stream>>>(out_proj_w, wob, D_MODEL * D_INNER);
  {
    int NT = D_MODEL / 128, MT = BT / 128;
    gemm_tn_kernel<true><<<NT * MT, 256, 0, stream>>>(
        ybf, wob, out, BT, D_MODEL, D_INNER, NT, MT);
  }
}

// Round 2
// 612.471 us; speedup vs baseline: 1.0033x; 1.0033x over previous
//
#include <hip/hip_runtime.h>

#define D_MODEL 2048
#define D_INNER 4096
#define D_STATE 128
#define HEADDIM 64
#define NHEADS 64
#define CONV_DIM 4352
#define D_IN_PROJ 8512
#define BB 2
#define TSEQ 2048
#define BT (BB*TSEQ)
#define NCHUNK 32
#define LCH 64
#define EPS_F 1e-5f

typedef __bf16 bf16x8 __attribute__((ext_vector_type(8)));
typedef float f32x4 __attribute__((ext_vector_type(4)));

__device__ __forceinline__ float bf2f(unsigned short u){
  unsigned int x = ((unsigned int)u) << 16;
  return __builtin_bit_cast(float, x);
}
__device__ __forceinline__ unsigned short f2bf(float f){
  unsigned int x = __builtin_bit_cast(unsigned int, f);
  x += 0x7fffu + ((x >> 16) & 1u);
  return (unsigned short)(x >> 16);
}

// async global->LDS, 16 B/lane: LDS dest = wave-uniform base + lane*16.
__device__ __forceinline__ void async_copy16(const unsigned short* g, unsigned short* l) {
  __builtin_amdgcn_global_load_lds(
      (const __attribute__((address_space(1))) unsigned int*)g,
      (__attribute__((address_space(3))) unsigned int*)l, 16, 0, 0);
}

// fp32 -> bf16 cast, 8 elems/thread. n % 8 == 0.
__global__ __launch_bounds__(256) void cast_kernel(
    const float* __restrict__ in, unsigned short* __restrict__ out, int n)
{
  int i = (blockIdx.x * 256 + threadIdx.x) * 8;
  if (i >= n) return;
  float4 a = *(const float4*)&in[i];
  float4 b = *(const float4*)&in[i + 4];
  unsigned short o[8] = { f2bf(a.x), f2bf(a.y), f2bf(a.z), f2bf(a.w),
                          f2bf(b.x), f2bf(b.y), f2bf(b.z), f2bf(b.w) };
  *(uint4*)&out[i] = *(uint4*)o;
}

// ---------------------------------------------------------------------------
// 256x256-tile GEMM, deep-pipelined (T3+T4+T5 structure).
// C[m,n] = sum_k A[m,k]*B[n,k].  8 waves (2M x 4N), per-wave out 128x64.
// K in 32-wide units; LDS = 4-slot ring per operand (slot 256x32 bf16, 16KB),
// staging 3 units ahead via global_load_lds; ONE counted s_waitcnt vmcnt(8)
// + barrier per unit (never drain to 0 in steady state); setprio around MFMA.
// Ledger (per wave, 4 loads/unit, FIFO): at start of unit u the outstanding
// loads are units u,u+1,u+2 (=12) -> vmcnt(8) retires exactly unit u; each
// wave waits for ITS OWN unit-u loads, then the barrier joins all waves, so
// the whole slot is valid after the barrier. Tail: vmcnt(4)/0.
// Swizzle (R1 fix): row stride is 64 B = 16 banks, so bank cluster =
// 16*(row&1) + 4*blk. XOR the 16B-block index with ((row>>1)&3) -- NOT
// (row&3), whose low bit cancels against the 16*(row&1) term (that was R1's
// 4-way conflict, 1.34e7 SQ_LDS_BANK_CONFLICT). With f(row)=(row>>1)&3 a
// quarter-wave's 16 lanes cover all 8 bank clusters exactly twice = free.
// Applied both sides (rule #21): pre-swizzled global source, swizzled read;
// f depends only on (lm>>1)&3 for every fragment base (16-aligned rows).
// N may exceed real columns (padded NT): stores guarded col<N; garbage B rows
// only feed accumulator lanes whose columns are >= N (never stored).
// ---------------------------------------------------------------------------
template <bool F32OUT>
__global__ __launch_bounds__(512, 2) void gemm256_kernel(
    const unsigned short* __restrict__ A, const unsigned short* __restrict__ Bm,
    void* __restrict__ Cout, int M, int N, int K, int NT, int MT)
{
  __shared__ __align__(16) unsigned short As[4][256 * 32];
  __shared__ __align__(16) unsigned short Bs[4][256 * 32];
  int tid = threadIdx.x;

  // band-swizzled grid (8-wide nt bands) for L2 locality
  int bid = blockIdx.x;
  int fullBands = NT >> 3;
  int blocksFull = fullBands * 8 * MT;
  int mt, nt;
  if (bid < blocksFull) {
    int band = bid / (8 * MT);
    int wI = bid - band * (8 * MT);
    nt = band * 8 + (wI & 7);
    mt = wI >> 3;
  } else {
    int rem = bid - blocksFull;
    int WL = NT - fullBands * 8;
    nt = fullBands * 8 + rem % WL;
    mt = rem / WL;
  }
  int m0 = mt * 256, n0 = nt * 256;

  int wid = tid >> 6, lane = tid & 63;
  int wm = wid >> 2, wn = wid & 3;              // wave tile: rows wm*128, cols wn*64
  int lm = lane & 15, kqb = lane >> 4;
  int rsw = (kqb ^ ((lm >> 1) & 3)) * 8;        // swizzled in-row short offset (R1 fix)

  // staging: thread covers (row=tid>>2, blk=tid&3) of a 128-row x 32-col issue;
  // source block pre-swizzled so LDS stays linear (wave-uniform dest + lane*16).
  int srow = tid >> 2;
  int sblk = (tid & 3) ^ ((srow >> 1) & 3);     // (R1 fix)
  const unsigned short* Ap = A + (size_t)(m0 + srow) * K + sblk * 8;
  const unsigned short* Bp = Bm + (size_t)(n0 + srow) * K + sblk * 8;

  f32x4 acc[8][4] = {};
  const int U = K >> 5;                         // 32-wide K units

  // prologue: issue units 0,1,2 (12 loads/wave in flight)
#pragma unroll
  for (int u = 0; u < 3; u++) {
    int ku = u << 5;
    async_copy16(Ap + ku, &As[u][wid * 512]);
    async_copy16(Ap + (size_t)128 * K + ku, &As[u][4096 + wid * 512]);
    async_copy16(Bp + ku, &Bs[u][wid * 512]);
    async_copy16(Bp + (size_t)128 * K + ku, &Bs[u][4096 + wid * 512]);
  }

  for (int u = 0; u < U; u++) {
    int s = u & 3;
    int left = U - 1 - u;
    if (left >= 2)      asm volatile("s_waitcnt vmcnt(8)" ::: "memory");
    else if (left == 1) asm volatile("s_waitcnt vmcnt(4)" ::: "memory");
    else                asm volatile("s_waitcnt vmcnt(0)" ::: "memory");
    __builtin_amdgcn_s_barrier();

    const unsigned short* Ab = &As[s][wm * 4096];
    const unsigned short* Bb = &Bs[s][(wn * 64) * 32];
    int up = u + 3;
    int kup = up << 5, sp = up & 3;

    // ---- phase 0: B frags (reused both phases) + A frags 0-3; stage A(u+3)
    bf16x8 bfr[4], af[4];
#pragma unroll
    for (int j = 0; j < 4; j++) bfr[j] = *(const bf16x8*)&Bb[(j * 16 + lm) * 32 + rsw];
#pragma unroll
    for (int i = 0; i < 4; i++) af[i] = *(const bf16x8*)&Ab[(i * 16 + lm) * 32 + rsw];
    if (up < U) {
      async_copy16(Ap + kup, &As[sp][wid * 512]);
      async_copy16(Ap + (size_t)128 * K + kup, &As[sp][4096 + wid * 512]);
    }
    __builtin_amdgcn_s_setprio(1);
#pragma unroll
    for (int i = 0; i < 4; i++)
#pragma unroll
      for (int j = 0; j < 4; j++)
        acc[i][j] = __builtin_amdgcn_mfma_f32_16x16x32_bf16(af[i], bfr[j], acc[i][j], 0, 0, 0);
    __builtin_amdgcn_s_setprio(0);
    __builtin_amdgcn_s_barrier();

    // ---- phase 1: A frags 4-7; stage B(u+3)
#pragma unroll
    for (int i = 0; i < 4; i++) af[i] = *(const bf16x8*)&Ab[((4 + i) * 16 + lm) * 32 + rsw];
    if (up < U) {
      async_copy16(Bp + kup, &Bs[sp][wid * 512]);
      async_copy16(Bp + (size_t)128 * K + kup, &Bs[sp][4096 + wid * 512]);
    }
    __builtin_amdgcn_s_setprio(1);
#pragma unroll
    for (int i = 0; i < 4; i++)
#pragma unroll
      for (int j = 0; j < 4; j++)
        acc[4 + i][j] = __builtin_amdgcn_mfma_f32_16x16x32_bf16(af[i], bfr[j], acc[4 + i][j], 0, 0, 0);
    __builtin_amdgcn_s_setprio(0);
    // no bottom barrier: next unit's vmcnt+barrier provides the separation
  }

  int rq = lane >> 4;
#pragma unroll
  for (int i = 0; i < 8; i++) {
#pragma unroll
    for (int j = 0; j < 4; j++) {
      int col = n0 + wn * 64 + j * 16 + lm;
      if (col < N) {
        int mrow = m0 + wm * 128 + i * 16 + rq * 4;
#pragma unroll
        for (int r = 0; r < 4; r++) {
          if (F32OUT) ((float*)Cout)[(size_t)(mrow + r) * N + col] = acc[i][j][r];
          else ((unsigned short*)Cout)[(size_t)(mrow + r) * N + col] = f2bf(acc[i][j][r]);
        }
      }
    }
  }
}

// C[m,n] = sum_k A[m,k]*B[n,k]; m97-style staging, XOR-8 LDS swizzle,
// band-swizzled grid. Kept for GEMM2 (N=2048: 256^2 tiles would leave
// half the CUs idle at 128 workgroups).
template <bool F32OUT>
__global__ __launch_bounds__(256) void gemm_tn_kernel(
    const unsigned short* __restrict__ A, const unsigned short* __restrict__ Bm,
    void* __restrict__ Cout, int M, int N, int K, int NT, int MT)
{
  __shared__ __align__(16) unsigned short As[128 * 64];
  __shared__ __align__(16) unsigned short Bs[128 * 64];
  int tid = threadIdx.x;

  int bid = blockIdx.x;
  int fullBands = NT >> 3;
  int blocksFull = fullBands * 8 * MT;
  int mt, nt;
  if (bid < blocksFull) {
    int band = bid / (8 * MT);
    int wI = bid - band * (8 * MT);
    nt = band * 8 + (wI & 7);
    mt = wI >> 3;
  } else {
    int rem = bid - blocksFull;
    int WL = NT - fullBands * 8;
    nt = fullBands * 8 + rem % WL;
    mt = rem / WL;
  }
  int m0 = mt * 128, n0 = nt * 128;

  int wave = tid >> 6, lane = tid & 63;
  int wm = wave >> 1, wn = wave & 1;
  int lm = lane & 15, kqb = lane >> 4;
  int sw = lm & 7;

  int lr = lane >> 3, lc = lane & 7, bg = lc ^ lr;
  const unsigned short* Ap = A + (size_t)(m0 + wave * 32 + lr) * K + bg * 8;
  const unsigned short* Bp = Bm + (size_t)(n0 + wave * 32 + lr) * K + bg * 8;

  f32x4 acc[4][4] = {};

  for (int k0 = 0; k0 < K; k0 += 64) {
#pragma unroll
    for (int q = 0; q < 4; q++) {
      async_copy16(Ap + (size_t)q * 8 * K + k0, &As[(wave * 32 + q * 8) * 64]);
      async_copy16(Bp + (size_t)q * 8 * K + k0, &Bs[(wave * 32 + q * 8) * 64]);
    }
    __syncthreads();
#pragma unroll
    for (int kk = 0; kk < 64; kk += 32) {
      int b0 = (kk >> 3) + kqb;
      int boff = (b0 ^ sw) * 8;
      bf16x8 af[4], bfr[4];
#pragma unroll
      for (int i = 0; i < 4; i++) af[i]  = *(const bf16x8*)&As[(wm * 64 + i * 16 + lm) * 64 + boff];
#pragma unroll
      for (int j = 0; j < 4; j++) bfr[j] = *(const bf16x8*)&Bs[(wn * 64 + j * 16 + lm) * 64 + boff];
#pragma unroll
      for (int i = 0; i < 4; i++)
#pragma unroll
        for (int j = 0; j < 4; j++)
          acc[i][j] = __builtin_amdgcn_mfma_f32_16x16x32_bf16(af[i], bfr[j], acc[i][j], 0, 0, 0);
    }
    __syncthreads();
  }

  int rq = lane >> 4;
#pragma unroll
  for (int i = 0; i < 4; i++) {
#pragma unroll
    for (int j = 0; j < 4; j++) {
      int col = n0 + wn * 64 + j * 16 + lm;
      if (col < N) {
        int mrow = m0 + wm * 64 + i * 16 + rq * 4;
#pragma unroll
        for (int r = 0; r < 4; r++) {
          if (F32OUT) ((float*)Cout)[(size_t)(mrow + r) * N + col] = acc[i][j][r];
          else ((unsigned short*)Cout)[(size_t)(mrow + r) * N + col] = f2bf(acc[i][j][r]);
        }
      }
    }
  }
}

// Depthwise causal conv (window 4) + bias + silu. B/C now stored bf16.
__global__ __launch_bounds__(256) void conv_silu_kernel(
    const unsigned short* __restrict__ zx, const float* __restrict__ conv_w,
    const float* __restrict__ conv_b, unsigned short* __restrict__ xconv,
    unsigned short* __restrict__ Bbf, unsigned short* __restrict__ Cbf)
{
  const int NG = CONV_DIM / 8;
  int gid = blockIdx.x * 256 + threadIdx.x;
  if (gid >= BT * NG) return;
  int cg = gid % NG; int bt = gid / NG;
  int t = bt % TSEQ;
  int c0 = cg * 8;

  float wgt[8][4];
#pragma unroll
  for (int i = 0; i < 8; i++)
#pragma unroll
    for (int k = 0; k < 4; k++) wgt[i][k] = conv_w[(c0 + i) * 4 + k];

  float acc[8];
#pragma unroll
  for (int i = 0; i < 8; i++) acc[i] = conv_b[c0 + i];

#pragma unroll
  for (int k = 0; k < 4; k++) {
    int ts = t - 3 + k;
    if (ts < 0) continue;
    unsigned short xv[8];
    *(uint4*)xv = *(const uint4*)&zx[(size_t)(bt - 3 + k) * D_IN_PROJ + D_INNER + c0];
#pragma unroll
    for (int i = 0; i < 8; i++) acc[i] = fmaf(bf2f(xv[i]), wgt[i][k], acc[i]);
  }

  unsigned short o[8];
#pragma unroll
  for (int i = 0; i < 8; i++) { float v = acc[i]; o[i] = f2bf(v / (1.f + expf(-v))); }
  if (c0 < D_INNER) {
    *(uint4*)&xconv[(size_t)bt * D_INNER + c0] = *(uint4*)o;
  } else if (c0 < D_INNER + D_STATE) {
    *(uint4*)&Bbf[(size_t)bt * D_STATE + (c0 - D_INNER)] = *(uint4*)o;
  } else {
    *(uint4*)&Cbf[(size_t)bt * D_STATE + (c0 - D_INNER - D_STATE)] = *(uint4*)o;
  }
}

// Fused: dt = softplus(dt_raw + bias); la = dt*A; per-chunk inclusive cumsum.
// One wave per (cb,h); lane = t within chunk.
__global__ __launch_bounds__(256) void dtcum_kernel(
    const unsigned short* __restrict__ zx, const float* __restrict__ dt_bias,
    const float* __restrict__ A_log, float* __restrict__ dtv, float* __restrict__ ca)
{
  int g = blockIdx.x * 4 + (threadIdx.x >> 6);   // g = cb*64 + h
  int lane = threadIdx.x & 63;
  int h = g & 63; int cb = g >> 6;
  size_t bt = (size_t)cb * 64 + lane;
  float xr = bf2f(zx[bt * D_IN_PROJ + D_INNER + CONV_DIM + h]) + dt_bias[h];
  float dt = (xr > 20.f) ? xr : log1pf(expf(xr));
  float v = dt * (-expf(A_log[h]));
#pragma unroll
  for (int off = 1; off < 64; off <<= 1) {
    float t = __shfl_up(v, off);
    if (lane >= off) v += t;
  }
  dtv[bt * NHEADS + h] = dt;
  ca[(size_t)g * 64 + lane] = v;
}

// G[i,j] = sum_n C[i,n]*B[j,n] per (b,chunk). Shared across heads (NGROUPS=1).
__global__ __launch_bounds__(256) void chunk_g_kernel(
    const unsigned short* __restrict__ Bbf, const unsigned short* __restrict__ Cbf,
    unsigned short* __restrict__ G)
{
  __shared__ __align__(16) unsigned short Cs[64][136];
  __shared__ __align__(16) unsigned short Bs2[64][136];
  int tid = threadIdx.x; int cb = blockIdx.x;
  size_t bt0 = (size_t)cb * 64;
  int row = tid >> 2, seg = (tid & 3) * 32;
#pragma unroll
  for (int u = 0; u < 32; u += 8) {
    *(uint4*)&Cs[row][seg + u]  = *(const uint4*)&Cbf[(bt0 + row) * 128 + seg + u];
    *(uint4*)&Bs2[row][seg + u] = *(const uint4*)&Bbf[(bt0 + row) * 128 + seg + u];
  }
  __syncthreads();
  int wave = tid >> 6, lane = tid & 63, lm = lane & 15, kq = (lane >> 4) * 8, rq = lane >> 4;
  f32x4 acc[4] = {};
#pragma unroll
  for (int ks = 0; ks < 4; ks++) {
    bf16x8 af = *(const bf16x8*)&Cs[wave * 16 + lm][ks * 32 + kq];
#pragma unroll
    for (int jt = 0; jt < 4; jt++) {
      bf16x8 bb = *(const bf16x8*)&Bs2[jt * 16 + lm][ks * 32 + kq];
      acc[jt] = __builtin_amdgcn_mfma_f32_16x16x32_bf16(af, bb, acc[jt], 0, 0, 0);
    }
  }
#pragma unroll
  for (int jt = 0; jt < 4; jt++)
#pragma unroll
    for (int r = 0; r < 4; r++) {
      int i = wave * 16 + rq * 4 + r, j = jt * 16 + lm;
      G[(size_t)cb * 4096 + i * 64 + j] = f2bf(acc[jt][r]);
    }
}

// S[p,n] = sum_j exp(ca63-ca[j])*dt[j]*x[j,p] * B[j,n]. 4 heads per block:
// Bn (shared across heads) staged once; Ax restaged per head.
__global__ __launch_bounds__(256) void chunk_state_kernel(
    const unsigned short* __restrict__ Bbf, const unsigned short* __restrict__ xconv,
    const float* __restrict__ dtv, const float* __restrict__ ca,
    unsigned short* __restrict__ S)
{
  __shared__ __align__(16) unsigned short Ax[64][72];
  __shared__ __align__(16) unsigned short Bn[128][72];
  int tid = threadIdx.x;
  int c = blockIdx.x & 31, hb = (blockIdx.x >> 5) & 15, b = blockIdx.x >> 9;
  int cb = b * 32 + c;
  size_t bt0 = (size_t)cb * 64;
  {
    int j = tid >> 2, nseg = (tid & 3) * 32;
    unsigned short bv[32];
#pragma unroll
    for (int u = 0; u < 32; u += 8)
      *(uint4*)&bv[u] = *(const uint4*)&Bbf[(bt0 + j) * 128 + nseg + u];
#pragma unroll
    for (int u = 0; u < 32; u++) Bn[nseg + u][j] = bv[u];
  }
  int wave = tid >> 6, lane = tid & 63, lm = lane & 15, kq = (lane >> 4) * 8, rq = lane >> 4;
  int j = tid >> 2, pseg = (tid & 3) * 16;
  for (int hh = 0; hh < 4; hh++) {
    int h = hb * 4 + hh;
    const float* cag = &ca[((size_t)cb * 64 + h) * 64];
    float wj = expf(cag[63] - cag[j]) * dtv[(bt0 + j) * 64 + h];
    unsigned short xv[16];
    *(uint4*)&xv[0] = *(const uint4*)&xconv[(bt0 + j) * 4096 + h * 64 + pseg];
    *(uint4*)&xv[8] = *(const uint4*)&xconv[(bt0 + j) * 4096 + h * 64 + pseg + 8];
    if (hh) __syncthreads();           // prior iteration's reads complete
#pragma unroll
    for (int q = 0; q < 16; q++) Ax[pseg + q][j] = f2bf(wj * bf2f(xv[q]));
    __syncthreads();
    f32x4 acc[8] = {};
#pragma unroll
    for (int ks = 0; ks < 2; ks++) {
      bf16x8 af = *(const bf16x8*)&Ax[wave * 16 + lm][ks * 32 + kq];
#pragma unroll
      for (int nt = 0; nt < 8; nt++) {
        bf16x8 bb = *(const bf16x8*)&Bn[nt * 16 + lm][ks * 32 + kq];
        acc[nt] = __builtin_amdgcn_mfma_f32_16x16x32_bf16(af, bb, acc[nt], 0, 0, 0);
      }
    }
    size_t sbase = ((size_t)(b * 64 + h) * 32 + c) * 8192;
#pragma unroll
    for (int nt = 0; nt < 8; nt++)
#pragma unroll
      for (int r = 0; r < 4; r++) {
        int p = wave * 16 + rq * 4 + r, n = nt * 16 + lm;
        S[sbase + p * 128 + n] = f2bf(acc[nt][r]);
      }
  }
}

// Sequential pass over 32 chunks: read S[c], write h_in[c] in place,
// h = exp(ca63_c)*h + S[c]. Per (b,h); thread owns 4 state elems.
__global__ __launch_bounds__(256) void state_pass_kernel(
    unsigned short* __restrict__ Shin, const float* __restrict__ ca)
{
  int part = blockIdx.x & 7, bh = blockIdx.x >> 3;
  int h = bh & 63, b = bh >> 6;
  int e0 = part * 1024 + threadIdx.x * 4;
  size_t base = (size_t)bh * 32 * 8192;
  float hc[4] = {0.f, 0.f, 0.f, 0.f};
  for (int c = 0; c < 32; c++) {
    float sc = expf(ca[(((size_t)(b * 32 + c)) * 64 + h) * 64 + 63]);
    size_t off = base + (size_t)c * 8192 + e0;
    uint2 sv = *(uint2*)&Shin[off];
    unsigned short* sp = (unsigned short*)&sv;
    unsigned short ho[4];
#pragma unroll
    for (int q = 0; q < 4; q++) ho[q] = f2bf(hc[q]);
    *(uint2*)&Shin[off] = *(uint2*)ho;
#pragma unroll
    for (int q = 0; q < 4; q++) hc[q] = sc * hc[q] + bf2f(sp[q]);
  }
}

// y[i,p] = sum_j M'[i,j]*x[j,p] + sum_n (C[i,n]e^ca_i)*hin[p,n] + Dskip*x[i,p]
// with dt folded into M' = G*exp(ca_i-ca_j)*dt_j. One K=192 MFMA per (b,h,c).
__global__ __launch_bounds__(256) void chunk_y_kernel(
    const unsigned short* __restrict__ G, const unsigned short* __restrict__ Cbf,
    const unsigned short* __restrict__ xconv, const float* __restrict__ dtv,
    const float* __restrict__ ca, const unsigned short* __restrict__ hin,
    const float* __restrict__ Dskip, unsigned short* __restrict__ yp)
{
  __shared__ __align__(16) unsigned short Aop[64][200];
  __shared__ __align__(16) unsigned short Bop[64][200];
  __shared__ float cas[64]; __shared__ float dts[64];
  int tid = threadIdx.x;
  int c = blockIdx.x & 31, h = (blockIdx.x >> 5) & 63, b = blockIdx.x >> 11;
  int cb = b * 32 + c;
  size_t bt0 = (size_t)cb * 64;
  if (tid < 64) {
    cas[tid] = ca[((size_t)cb * 64 + h) * 64 + tid];
    dts[tid] = dtv[(bt0 + tid) * 64 + h];
  }
  __syncthreads();
  {
    int i = tid >> 2, jseg = (tid & 3) * 16;
    float cai = cas[i];
    unsigned short gv[16];
    *(uint4*)&gv[0] = *(const uint4*)&G[(size_t)cb * 4096 + i * 64 + jseg];
    *(uint4*)&gv[8] = *(const uint4*)&G[(size_t)cb * 4096 + i * 64 + jseg + 8];
    unsigned short o[16];
#pragma unroll
    for (int q = 0; q < 16; q++) {
      int j = jseg + q;
      float m = (j <= i) ? bf2f(gv[q]) * expf(cai - cas[j]) * dts[j] : 0.f;
      o[q] = f2bf(m);
    }
    *(uint4*)&Aop[i][jseg] = *(uint4*)&o[0];
    *(uint4*)&Aop[i][jseg + 8] = *(uint4*)&o[8];
  }
  {
    int i = tid >> 2, nseg = (tid & 3) * 32;
    float sci = expf(cas[i]);
#pragma unroll
    for (int u = 0; u < 32; u += 8) {
      unsigned short cv[8];
      *(uint4*)cv = *(const uint4*)&Cbf[(bt0 + i) * 128 + nseg + u];
      unsigned short o[8];
#pragma unroll
      for (int q = 0; q < 8; q++) o[q] = f2bf(sci * bf2f(cv[q]));
      *(uint4*)&Aop[i][64 + nseg + u] = *(uint4*)o;
    }
  }
  {
    int j = tid >> 2, pseg = (tid & 3) * 16;
    unsigned short xv[16];
    *(uint4*)&xv[0] = *(const uint4*)&xconv[(bt0 + j) * 4096 + h * 64 + pseg];
    *(uint4*)&xv[8] = *(const uint4*)&xconv[(bt0 + j) * 4096 + h * 64 + pseg + 8];
#pragma unroll
    for (int q = 0; q < 16; q++) Bop[pseg + q][j] = xv[q];
  }
  {
    int p = tid >> 2, nseg = (tid & 3) * 32;
    size_t hb = ((size_t)(b * 64 + h) * 32 + c) * 8192 + p * 128 + nseg;
#pragma unroll
    for (int u = 0; u < 32; u += 8)
      *(uint4*)&Bop[p][64 + nseg + u] = *(const uint4*)&hin[hb + u];
  }
  __syncthreads();
  int wave = tid >> 6, lane = tid & 63, lm = lane & 15, kq = (lane >> 4) * 8, rq = lane >> 4;
  f32x4 acc[4] = {};
#pragma unroll
  for (int ks = 0; ks < 6; ks++) {
    bf16x8 af = *(const bf16x8*)&Aop[wave * 16 + lm][ks * 32 + kq];
#pragma unroll
    for (int pt = 0; pt < 4; pt++) {
      bf16x8 bb = *(const bf16x8*)&Bop[pt * 16 + lm][ks * 32 + kq];
      acc[pt] = __builtin_amdgcn_mfma_f32_16x16x32_bf16(af, bb, acc[pt], 0, 0, 0);
    }
  }
  float dsk = Dskip[h];
#pragma unroll
  for (int pt = 0; pt < 4; pt++)
#pragma unroll
    for (int r = 0; r < 4; r++) {
      int i = wave * 16 + rq * 4 + r, p = pt * 16 + lm;
      float y = acc[pt][r] + dsk * bf2f(Bop[p][i]);   // Bop[p][i] = x[i,p]
      yp[(bt0 + i) * 4096 + h * 64 + p] = f2bf(y);
    }
}

// gate with silu(z), rmsnorm, write bf16.
__global__ __launch_bounds__(256) void gate_norm_kernel(
    const unsigned short* __restrict__ yp, const unsigned short* __restrict__ zx,
    const float* __restrict__ norm_w, unsigned short* __restrict__ ybf)
{
  int row = blockIdx.x; int tid = threadIdx.x;
  int c0 = tid * 16;
  unsigned short y0[16], zv[16];
  const size_t base = (size_t)row * D_INNER + c0;
  *(uint4*)&y0[0] = *(const uint4*)&yp[base];
  *(uint4*)&y0[8] = *(const uint4*)&yp[base + 8];
  const size_t zbase = (size_t)row * D_IN_PROJ + c0;
  *(uint4*)&zv[0] = *(const uint4*)&zx[zbase];
  *(uint4*)&zv[8] = *(const uint4*)&zx[zbase + 8];

  float g[16]; float ss = 0.f;
#pragma unroll
  for (int i = 0; i < 16; i++) {
    float y = bf2f(y0[i]);
    float z = bf2f(zv[i]);
    float gate = z / (1.f + expf(-z));
    float gv = y * gate;
    g[i] = gv; ss += gv * gv;
  }
#pragma unroll
  for (int o = 32; o >= 1; o >>= 1) ss += __shfl_xor(ss, o);
  __shared__ float red[4]; __shared__ float stot;
  if ((tid & 63) == 0) red[tid >> 6] = ss;
  __syncthreads();
  if (tid == 0) stot = red[0] + red[1] + red[2] + red[3];
  __syncthreads();
  float scale = rsqrtf(stot * (1.f / D_INNER) + EPS_F);
  unsigned short o16[16];
#pragma unroll
  for (int i = 0; i < 16; i++) o16[i] = f2bf(g[i] * scale * norm_w[c0 + i]);
  *(uint4*)&ybf[base] = *(uint4*)&o16[0];
  *(uint4*)&ybf[base + 8] = *(uint4*)&o16[8];
}

extern "C" void kernel_launch(void* const* d_in, const int* in_sizes, int n_in,
                              void* d_out, int out_size, void* d_ws, size_t ws_size,
                              hipStream_t stream) {
  (void)in_sizes; (void)n_in; (void)out_size; (void)ws_size;
  const float* x          = (const float*)d_in[0];
  const float* in_proj_w  = (const float*)d_in[3];
  const float* conv_w     = (const float*)d_in[4];
  const float* conv_b     = (const float*)d_in[5];
  const float* dt_bias    = (const float*)d_in[6];
  const float* A_log      = (const float*)d_in[7];
  const float* Dskip      = (const float*)d_in[8];
  const float* norm_w     = (const float*)d_in[9];
  const float* out_proj_w = (const float*)d_in[10];
  float* out = (float*)d_out;

  char* w = (char*)d_ws;
  unsigned short* zx    = (unsigned short*)(w);
  unsigned short* xconv = (unsigned short*)(w + 69730304);
  unsigned short* Bbf = (unsigned short*)(w + 103284736);   // BT*128 bf16
  unsigned short* Cbf = (unsigned short*)(w + 105381888);   // BT*128 bf16
  float* dtv = (float*)(w + 107479040);
  float* ca  = (float*)(w + 109576192);
  unsigned short* G    = (unsigned short*)(w + 110624768);
  unsigned short* Shin = (unsigned short*)(w + 111149056);
  unsigned short* yp   = (unsigned short*)(w + 178257920);
  unsigned short* xb   = (unsigned short*)(w + 111149056);   // pre-scan overlay
  unsigned short* wib  = (unsigned short*)(w + 127926272);   // pre-scan overlay (padded to 8704 rows)
  unsigned short* ybf  = (unsigned short*)(w + 111149056);   // post-scan overlay
  unsigned short* wob  = (unsigned short*)(w + 144703488);   // post-scan overlay

  cast_kernel<<<BT * D_MODEL / 8 / 256, 256, 0, stream>>>(x, xb, BT * D_MODEL);
  cast_kernel<<<D_IN_PROJ * D_MODEL / 8 / 256, 256, 0, stream>>>(in_proj_w, wib, D_IN_PROJ * D_MODEL);
  {
    // 256^2 deep-pipelined GEMM; N padded to 34 tiles (8704). Rows 8512..8703
    // of wib are garbage: they feed only accumulator columns >= N (store-guarded).
    int NT = 34, MT = BT / 256;
    gemm256_kernel<false><<<NT * MT, 512, 0, stream>>>(
        xb, wib, zx, BT, D_IN_PROJ, D_MODEL, NT, MT);
  }
  conv_silu_kernel<<<(BT * (CONV_DIM / 8) + 255) / 256, 256, 0, stream>>>(
      zx, conv_w, conv_b, xconv, Bbf, Cbf);
  dtcum_kernel<<<BB * NCHUNK * NHEADS / 4, 256, 0, stream>>>(zx, dt_bias, A_log, dtv, ca);
  chunk_g_kernel<<<BB * NCHUNK, 256, 0, stream>>>(Bbf, Cbf, G);
  chunk_state_kernel<<<BB * 16 * NCHUNK, 256, 0, stream>>>(Bbf, xconv, dtv, ca, Shin);
  state_pass_kernel<<<BB * NHEADS * 8, 256, 0, stream>>>(Shin, ca);
  chunk_y_kernel<<<BB * NHEADS * NCHUNK, 256, 0, stream>>>(G, Cbf, xconv, dtv, ca, Shin, Dskip, yp);
  gate_norm_kernel<<<BT, 256, 0, stream>>>(yp, zx, norm_w, ybf);
  cast_kernel<<<D_MODEL * D_INNER / 8 / 256, 256, 0, stream>>>(out_proj_w, wob, D_MODEL * D_INNER);
  {
    int NT = D_MODEL / 128, MT = BT / 128;
    gemm_tn_kernel<true><<<NT * MT, 256, 0, stream>>>(
        ybf, wob, out, BT, D_MODEL, D_INNER, NT, MT);
  }
}

// Round 3
// 602.626 us; speedup vs baseline: 1.0197x; 1.0163x over previous
//
#include <hip/hip_runtime.h>

#define D_MODEL 2048
#define D_INNER 4096
#define D_STATE 128
#define HEADDIM 64
#define NHEADS 64
#define CONV_DIM 4352
#define D_IN_PROJ 8512
#define BB 2
#define TSEQ 2048
#define BT (BB*TSEQ)
#define NCHUNK 32
#define LCH 64
#define EPS_F 1e-5f

typedef __bf16 bf16x8 __attribute__((ext_vector_type(8)));
typedef float f32x4 __attribute__((ext_vector_type(4)));

__device__ __forceinline__ float bf2f(unsigned short u){
  unsigned int x = ((unsigned int)u) << 16;
  return __builtin_bit_cast(float, x);
}
__device__ __forceinline__ unsigned short f2bf(float f){
  unsigned int x = __builtin_bit_cast(unsigned int, f);
  x += 0x7fffu + ((x >> 16) & 1u);
  return (unsigned short)(x >> 16);
}

// async global->LDS, 16 B/lane: LDS dest = wave-uniform base + lane*16.
__device__ __forceinline__ void async_copy16(const unsigned short* g, unsigned short* l) {
  __builtin_amdgcn_global_load_lds(
      (const __attribute__((address_space(1))) unsigned int*)g,
      (__attribute__((address_space(3))) unsigned int*)l, 16, 0, 0);
}

// fp32 -> bf16 cast, 8 elems/thread. n % 8 == 0.
__global__ __launch_bounds__(256) void cast_kernel(
    const float* __restrict__ in, unsigned short* __restrict__ out, int n)
{
  int i = (blockIdx.x * 256 + threadIdx.x) * 8;
  if (i >= n) return;
  float4 a = *(const float4*)&in[i];
  float4 b = *(const float4*)&in[i + 4];
  unsigned short o[8] = { f2bf(a.x), f2bf(a.y), f2bf(a.z), f2bf(a.w),
                          f2bf(b.x), f2bf(b.y), f2bf(b.z), f2bf(b.w) };
  *(uint4*)&out[i] = *(uint4*)o;
}

// ---------------------------------------------------------------------------
// 256x256-tile GEMM, deep-pipelined, register-double-buffered fragments (R2).
// C[m,n] = sum_k A[m,k]*B[n,k].  8 waves (2M x 4N), per-wave out 128x64.
// K in 32-wide units; LDS = 4-slot ring per operand (slot 256x32 bf16, 16KB),
// staging 3 units ahead via global_load_lds. ONE barrier per unit.
//
// R2 structural fix: every MFMA cluster consumes fragments whose ds_reads
// were ISSUED >=1 phase (>=620cy of MFMA shadow) earlier, so LDS serves
// under the MFMA-issue shadow instead of alternating with it (R1/R2 showed
// strict alternation caps MfmaUtil at ~32%). Per unit u:
//   phase0: read A-hi(u) [4]; stage A(u+3); MFMA-lo(u) (uses regs from
//           phase1 of u-1); vmcnt(sel); barrier   <- slot u+1 now valid
//   phase1: read B(u+1)+A-lo(u+1) [8] from slot u+1; stage B(u+3);
//           MFMA-hi(u) (uses A-hi read in phase0)
// Register ping-pong via 2x-unrolled body (U even), no copies, all indices
// compile-time (rule #20).
//
// vmcnt ledger (per wave, FIFO, 4 loads/unit, A-pair issued phase0, B-pair
// phase1): before the wait at phase0 of u, outstanding = units u+1,u+2 (4
// each, if they exist) + A(u+3) (2, if exists); retiring unit u+1 leaves
//   u<=U-4: 6   u==U-3: 4   u>=U-2: 0
// Slot-reuse separation (>=1 barrier between last read of a slot and its
// restaging write + vmem latency): A(u+3)->slot(u-1): last reads A-hi(u-1)
// phase0 of u-1 (pre mid-(u-1) barrier) and A-lo/B(u-1) phase1 of u-2;
// stage issues phase0 of u (post mid-(u-1) barrier). B(u+3)->slot(u-1):
// last B-read phase1 of u-2, >=2 barriers before the phase1-of-u stage.
// Swizzle: unchanged R1 fix (zero conflicts measured): 16B-block ^=
// ((row>>1)&3), both sides (pre-swizzled global source + swizzled read).
// N may exceed real columns (padded NT): stores guarded col<N.
// Requires U = K/32 even (K=2048 here -> U=64).
// ---------------------------------------------------------------------------
#define GUNIT(u_, CA, CB, NA, NB)                                              \
  {                                                                            \
    const int s_ = (u_) & 3;                                                   \
    const int up_ = (u_) + 3;                                                  \
    const unsigned short* Ab_ = &As[s_][wm * 4096];                            \
    _Pragma("unroll")                                                          \
    for (int i = 0; i < 4; i++)                                                \
      aD[i] = *(const bf16x8*)&Ab_[((4 + i) * 16 + lm) * 32 + rsw];            \
    if (up_ < U) {                                                             \
      int kup_ = up_ << 5; int sp_ = up_ & 3;                                  \
      async_copy16(Ap + kup_, &As[sp_][wid * 512]);                            \
      async_copy16(Ap + (size_t)128 * K + kup_, &As[sp_][4096 + wid * 512]);   \
    }                                                                          \
    __builtin_amdgcn_s_setprio(1);                                             \
    _Pragma("unroll")                                                          \
    for (int i = 0; i < 4; i++)                                                \
      _Pragma("unroll")                                                        \
      for (int j = 0; j < 4; j++)                                              \
        acc[i][j] = __builtin_amdgcn_mfma_f32_16x16x32_bf16(                   \
            CA[i], CB[j], acc[i][j], 0, 0, 0);                                 \
    __builtin_amdgcn_s_setprio(0);                                             \
    {                                                                          \
      int left_ = U - 1 - (u_);                                                \
      if (left_ >= 3)      asm volatile("s_waitcnt vmcnt(6)" ::: "memory");    \
      else if (left_ == 2) asm volatile("s_waitcnt vmcnt(4)" ::: "memory");    \
      else                 asm volatile("s_waitcnt vmcnt(0)" ::: "memory");    \
    }                                                                          \
    __builtin_amdgcn_s_barrier();                                              \
    if ((u_) + 1 < U) {                                                        \
      const int sn_ = ((u_) + 1) & 3;                                          \
      const unsigned short* Abn_ = &As[sn_][wm * 4096];                        \
      const unsigned short* Bbn_ = &Bs[sn_][(wn * 64) * 32];                   \
      _Pragma("unroll")                                                        \
      for (int j = 0; j < 4; j++)                                              \
        NB[j] = *(const bf16x8*)&Bbn_[(j * 16 + lm) * 32 + rsw];               \
      _Pragma("unroll")                                                        \
      for (int i = 0; i < 4; i++)                                              \
        NA[i] = *(const bf16x8*)&Abn_[(i * 16 + lm) * 32 + rsw];               \
    }                                                                          \
    if (up_ < U) {                                                             \
      int kup_ = up_ << 5; int sp_ = up_ & 3;                                  \
      async_copy16(Bp + kup_, &Bs[sp_][wid * 512]);                            \
      async_copy16(Bp + (size_t)128 * K + kup_, &Bs[sp_][4096 + wid * 512]);   \
    }                                                                          \
    __builtin_amdgcn_s_setprio(1);                                             \
    _Pragma("unroll")                                                          \
    for (int i = 0; i < 4; i++)                                                \
      _Pragma("unroll")                                                        \
      for (int j = 0; j < 4; j++)                                              \
        acc[4 + i][j] = __builtin_amdgcn_mfma_f32_16x16x32_bf16(               \
            aD[i], CB[j], acc[4 + i][j], 0, 0, 0);                             \
    __builtin_amdgcn_s_setprio(0);                                             \
  }

template <bool F32OUT>
__global__ __launch_bounds__(512, 2) void gemm256_kernel(
    const unsigned short* __restrict__ A, const unsigned short* __restrict__ Bm,
    void* __restrict__ Cout, int M, int N, int K, int NT, int MT)
{
  __shared__ __align__(16) unsigned short As[4][256 * 32];
  __shared__ __align__(16) unsigned short Bs[4][256 * 32];
  int tid = threadIdx.x;

  // band-swizzled grid (8-wide nt bands) for L2 locality
  int bid = blockIdx.x;
  int fullBands = NT >> 3;
  int blocksFull = fullBands * 8 * MT;
  int mt, nt;
  if (bid < blocksFull) {
    int band = bid / (8 * MT);
    int wI = bid - band * (8 * MT);
    nt = band * 8 + (wI & 7);
    mt = wI >> 3;
  } else {
    int rem = bid - blocksFull;
    int WL = NT - fullBands * 8;
    nt = fullBands * 8 + rem % WL;
    mt = rem / WL;
  }
  int m0 = mt * 256, n0 = nt * 256;

  int wid = tid >> 6, lane = tid & 63;
  int wm = wid >> 2, wn = wid & 3;              // wave tile: rows wm*128, cols wn*64
  int lm = lane & 15, kqb = lane >> 4;
  int rsw = (kqb ^ ((lm >> 1) & 3)) * 8;        // swizzled in-row short offset

  // staging: thread covers (row=tid>>2, blk=tid&3) of a 128-row x 32-col issue;
  // source block pre-swizzled so LDS stays linear (wave-uniform dest + lane*16).
  int srow = tid >> 2;
  int sblk = (tid & 3) ^ ((srow >> 1) & 3);
  const unsigned short* Ap = A + (size_t)(m0 + srow) * K + sblk * 8;
  const unsigned short* Bp = Bm + (size_t)(n0 + srow) * K + sblk * 8;

  f32x4 acc[8][4] = {};
  const int U = K >> 5;                         // 32-wide K units (must be even)

  // prologue: issue units 0,1,2 (12 loads/wave in flight)
#pragma unroll
  for (int u = 0; u < 3; u++) {
    int ku = u << 5;
    async_copy16(Ap + ku, &As[u][wid * 512]);
    async_copy16(Ap + (size_t)128 * K + ku, &As[u][4096 + wid * 512]);
    async_copy16(Bp + ku, &Bs[u][wid * 512]);
    async_copy16(Bp + (size_t)128 * K + ku, &Bs[u][4096 + wid * 512]);
  }

  bf16x8 aC[4], bC[4], aN[4], bN[4], aD[4];

  // unit 0 ready; preload its lo-half fragments
  asm volatile("s_waitcnt vmcnt(8)" ::: "memory");
  __builtin_amdgcn_s_barrier();
  {
    const unsigned short* Ab0 = &As[0][wm * 4096];
    const unsigned short* Bb0 = &Bs[0][(wn * 64) * 32];
#pragma unroll
    for (int j = 0; j < 4; j++) bC[j] = *(const bf16x8*)&Bb0[(j * 16 + lm) * 32 + rsw];
#pragma unroll
    for (int i = 0; i < 4; i++) aC[i] = *(const bf16x8*)&Ab0[(i * 16 + lm) * 32 + rsw];
  }

  for (int u = 0; u < U; u += 2) {
    GUNIT(u,     aC, bC, aN, bN);
    GUNIT(u + 1, aN, bN, aC, bC);
  }

  int rq = lane >> 4;
#pragma unroll
  for (int i = 0; i < 8; i++) {
#pragma unroll
    for (int j = 0; j < 4; j++) {
      int col = n0 + wn * 64 + j * 16 + lm;
      if (col < N) {
        int mrow = m0 + wm * 128 + i * 16 + rq * 4;
#pragma unroll
        for (int r = 0; r < 4; r++) {
          if (F32OUT) ((float*)Cout)[(size_t)(mrow + r) * N + col] = acc[i][j][r];
          else ((unsigned short*)Cout)[(size_t)(mrow + r) * N + col] = f2bf(acc[i][j][r]);
        }
      }
    }
  }
}

// C[m,n] = sum_k A[m,k]*B[n,k]; m97-style staging, XOR-8 LDS swizzle,
// band-swizzled grid. Kept for GEMM2 (N=2048: 256^2 tiles would leave
// half the CUs idle at 128 workgroups).
template <bool F32OUT>
__global__ __launch_bounds__(256) void gemm_tn_kernel(
    const unsigned short* __restrict__ A, const unsigned short* __restrict__ Bm,
    void* __restrict__ Cout, int M, int N, int K, int NT, int MT)
{
  __shared__ __align__(16) unsigned short As[128 * 64];
  __shared__ __align__(16) unsigned short Bs[128 * 64];
  int tid = threadIdx.x;

  int bid = blockIdx.x;
  int fullBands = NT >> 3;
  int blocksFull = fullBands * 8 * MT;
  int mt, nt;
  if (bid < blocksFull) {
    int band = bid / (8 * MT);
    int wI = bid - band * (8 * MT);
    nt = band * 8 + (wI & 7);
    mt = wI >> 3;
  } else {
    int rem = bid - blocksFull;
    int WL = NT - fullBands * 8;
    nt = fullBands * 8 + rem % WL;
    mt = rem / WL;
  }
  int m0 = mt * 128, n0 = nt * 128;

  int wave = tid >> 6, lane = tid & 63;
  int wm = wave >> 1, wn = wave & 1;
  int lm = lane & 15, kqb = lane >> 4;
  int sw = lm & 7;

  int lr = lane >> 3, lc = lane & 7, bg = lc ^ lr;
  const unsigned short* Ap = A + (size_t)(m0 + wave * 32 + lr) * K + bg * 8;
  const unsigned short* Bp = Bm + (size_t)(n0 + wave * 32 + lr) * K + bg * 8;

  f32x4 acc[4][4] = {};

  for (int k0 = 0; k0 < K; k0 += 64) {
#pragma unroll
    for (int q = 0; q < 4; q++) {
      async_copy16(Ap + (size_t)q * 8 * K + k0, &As[(wave * 32 + q * 8) * 64]);
      async_copy16(Bp + (size_t)q * 8 * K + k0, &Bs[(wave * 32 + q * 8) * 64]);
    }
    __syncthreads();
#pragma unroll
    for (int kk = 0; kk < 64; kk += 32) {
      int b0 = (kk >> 3) + kqb;
      int boff = (b0 ^ sw) * 8;
      bf16x8 af[4], bfr[4];
#pragma unroll
      for (int i = 0; i < 4; i++) af[i]  = *(const bf16x8*)&As[(wm * 64 + i * 16 + lm) * 64 + boff];
#pragma unroll
      for (int j = 0; j < 4; j++) bfr[j] = *(const bf16x8*)&Bs[(wn * 64 + j * 16 + lm) * 64 + boff];
#pragma unroll
      for (int i = 0; i < 4; i++)
#pragma unroll
        for (int j = 0; j < 4; j++)
          acc[i][j] = __builtin_amdgcn_mfma_f32_16x16x32_bf16(af[i], bfr[j], acc[i][j], 0, 0, 0);
    }
    __syncthreads();
  }

  int rq = lane >> 4;
#pragma unroll
  for (int i = 0; i < 4; i++) {
#pragma unroll
    for (int j = 0; j < 4; j++) {
      int col = n0 + wn * 64 + j * 16 + lm;
      if (col < N) {
        int mrow = m0 + wm * 64 + i * 16 + rq * 4;
#pragma unroll
        for (int r = 0; r < 4; r++) {
          if (F32OUT) ((float*)Cout)[(size_t)(mrow + r) * N + col] = acc[i][j][r];
          else ((unsigned short*)Cout)[(size_t)(mrow + r) * N + col] = f2bf(acc[i][j][r]);
        }
      }
    }
  }
}

// Depthwise causal conv (window 4) + bias + silu. B/C now stored bf16.
__global__ __launch_bounds__(256) void conv_silu_kernel(
    const unsigned short* __restrict__ zx, const float* __restrict__ conv_w,
    const float* __restrict__ conv_b, unsigned short* __restrict__ xconv,
    unsigned short* __restrict__ Bbf, unsigned short* __restrict__ Cbf)
{
  const int NG = CONV_DIM / 8;
  int gid = blockIdx.x * 256 + threadIdx.x;
  if (gid >= BT * NG) return;
  int cg = gid % NG; int bt = gid / NG;
  int t = bt % TSEQ;
  int c0 = cg * 8;

  float wgt[8][4];
#pragma unroll
  for (int i = 0; i < 8; i++)
#pragma unroll
    for (int k = 0; k < 4; k++) wgt[i][k] = conv_w[(c0 + i) * 4 + k];

  float acc[8];
#pragma unroll
  for (int i = 0; i < 8; i++) acc[i] = conv_b[c0 + i];

#pragma unroll
  for (int k = 0; k < 4; k++) {
    int ts = t - 3 + k;
    if (ts < 0) continue;
    unsigned short xv[8];
    *(uint4*)xv = *(const uint4*)&zx[(size_t)(bt - 3 + k) * D_IN_PROJ + D_INNER + c0];
#pragma unroll
    for (int i = 0; i < 8; i++) acc[i] = fmaf(bf2f(xv[i]), wgt[i][k], acc[i]);
  }

  unsigned short o[8];
#pragma unroll
  for (int i = 0; i < 8; i++) { float v = acc[i]; o[i] = f2bf(v / (1.f + expf(-v))); }
  if (c0 < D_INNER) {
    *(uint4*)&xconv[(size_t)bt * D_INNER + c0] = *(uint4*)o;
  } else if (c0 < D_INNER + D_STATE) {
    *(uint4*)&Bbf[(size_t)bt * D_STATE + (c0 - D_INNER)] = *(uint4*)o;
  } else {
    *(uint4*)&Cbf[(size_t)bt * D_STATE + (c0 - D_INNER - D_STATE)] = *(uint4*)o;
  }
}

// Fused: dt = softplus(dt_raw + bias); la = dt*A; per-chunk inclusive cumsum.
// One wave per (cb,h); lane = t within chunk.
__global__ __launch_bounds__(256) void dtcum_kernel(
    const unsigned short* __restrict__ zx, const float* __restrict__ dt_bias,
    const float* __restrict__ A_log, float* __restrict__ dtv, float* __restrict__ ca)
{
  int g = blockIdx.x * 4 + (threadIdx.x >> 6);   // g = cb*64 + h
  int lane = threadIdx.x & 63;
  int h = g & 63; int cb = g >> 6;
  size_t bt = (size_t)cb * 64 + lane;
  float xr = bf2f(zx[bt * D_IN_PROJ + D_INNER + CONV_DIM + h]) + dt_bias[h];
  float dt = (xr > 20.f) ? xr : log1pf(expf(xr));
  float v = dt * (-expf(A_log[h]));
#pragma unroll
  for (int off = 1; off < 64; off <<= 1) {
    float t = __shfl_up(v, off);
    if (lane >= off) v += t;
  }
  dtv[bt * NHEADS + h] = dt;
  ca[(size_t)g * 64 + lane] = v;
}

// G[i,j] = sum_n C[i,n]*B[j,n] per (b,chunk). Shared across heads (NGROUPS=1).
__global__ __launch_bounds__(256) void chunk_g_kernel(
    const unsigned short* __restrict__ Bbf, const unsigned short* __restrict__ Cbf,
    unsigned short* __restrict__ G)
{
  __shared__ __align__(16) unsigned short Cs[64][136];
  __shared__ __align__(16) unsigned short Bs2[64][136];
  int tid = threadIdx.x; int cb = blockIdx.x;
  size_t bt0 = (size_t)cb * 64;
  int row = tid >> 2, seg = (tid & 3) * 32;
#pragma unroll
  for (int u = 0; u < 32; u += 8) {
    *(uint4*)&Cs[row][seg + u]  = *(const uint4*)&Cbf[(bt0 + row) * 128 + seg + u];
    *(uint4*)&Bs2[row][seg + u] = *(const uint4*)&Bbf[(bt0 + row) * 128 + seg + u];
  }
  __syncthreads();
  int wave = tid >> 6, lane = tid & 63, lm = lane & 15, kq = (lane >> 4) * 8, rq = lane >> 4;
  f32x4 acc[4] = {};
#pragma unroll
  for (int ks = 0; ks < 4; ks++) {
    bf16x8 af = *(const bf16x8*)&Cs[wave * 16 + lm][ks * 32 + kq];
#pragma unroll
    for (int jt = 0; jt < 4; jt++) {
      bf16x8 bb = *(const bf16x8*)&Bs2[jt * 16 + lm][ks * 32 + kq];
      acc[jt] = __builtin_amdgcn_mfma_f32_16x16x32_bf16(af, bb, acc[jt], 0, 0, 0);
    }
  }
#pragma unroll
  for (int jt = 0; jt < 4; jt++)
#pragma unroll
    for (int r = 0; r < 4; r++) {
      int i = wave * 16 + rq * 4 + r, j = jt * 16 + lm;
      G[(size_t)cb * 4096 + i * 64 + j] = f2bf(acc[jt][r]);
    }
}

// S[p,n] = sum_j exp(ca63-ca[j])*dt[j]*x[j,p] * B[j,n]. 4 heads per block:
// Bn (shared across heads) staged once; Ax restaged per head.
__global__ __launch_bounds__(256) void chunk_state_kernel(
    const unsigned short* __restrict__ Bbf, const unsigned short* __restrict__ xconv,
    const float* __restrict__ dtv, const float* __restrict__ ca,
    unsigned short* __restrict__ S)
{
  __shared__ __align__(16) unsigned short Ax[64][72];
  __shared__ __align__(16) unsigned short Bn[128][72];
  int tid = threadIdx.x;
  int c = blockIdx.x & 31, hb = (blockIdx.x >> 5) & 15, b = blockIdx.x >> 9;
  int cb = b * 32 + c;
  size_t bt0 = (size_t)cb * 64;
  {
    int j = tid >> 2, nseg = (tid & 3) * 32;
    unsigned short bv[32];
#pragma unroll
    for (int u = 0; u < 32; u += 8)
      *(uint4*)&bv[u] = *(const uint4*)&Bbf[(bt0 + j) * 128 + nseg + u];
#pragma unroll
    for (int u = 0; u < 32; u++) Bn[nseg + u][j] = bv[u];
  }
  int wave = tid >> 6, lane = tid & 63, lm = lane & 15, kq = (lane >> 4) * 8, rq = lane >> 4;
  int j = tid >> 2, pseg = (tid & 3) * 16;
  for (int hh = 0; hh < 4; hh++) {
    int h = hb * 4 + hh;
    const float* cag = &ca[((size_t)cb * 64 + h) * 64];
    float wj = expf(cag[63] - cag[j]) * dtv[(bt0 + j) * 64 + h];
    unsigned short xv[16];
    *(uint4*)&xv[0] = *(const uint4*)&xconv[(bt0 + j) * 4096 + h * 64 + pseg];
    *(uint4*)&xv[8] = *(const uint4*)&xconv[(bt0 + j) * 4096 + h * 64 + pseg + 8];
    if (hh) __syncthreads();           // prior iteration's reads complete
#pragma unroll
    for (int q = 0; q < 16; q++) Ax[pseg + q][j] = f2bf(wj * bf2f(xv[q]));
    __syncthreads();
    f32x4 acc[8] = {};
#pragma unroll
    for (int ks = 0; ks < 2; ks++) {
      bf16x8 af = *(const bf16x8*)&Ax[wave * 16 + lm][ks * 32 + kq];
#pragma unroll
      for (int nt = 0; nt < 8; nt++) {
        bf16x8 bb = *(const bf16x8*)&Bn[nt * 16 + lm][ks * 32 + kq];
        acc[nt] = __builtin_amdgcn_mfma_f32_16x16x32_bf16(af, bb, acc[nt], 0, 0, 0);
      }
    }
    size_t sbase = ((size_t)(b * 64 + h) * 32 + c) * 8192;
#pragma unroll
    for (int nt = 0; nt < 8; nt++)
#pragma unroll
      for (int r = 0; r < 4; r++) {
        int p = wave * 16 + rq * 4 + r, n = nt * 16 + lm;
        S[sbase + p * 128 + n] = f2bf(acc[nt][r]);
      }
  }
}

// Sequential pass over 32 chunks: read S[c], write h_in[c] in place,
// h = exp(ca63_c)*h + S[c]. Per (b,h); thread owns 4 state elems.
__global__ __launch_bounds__(256) void state_pass_kernel(
    unsigned short* __restrict__ Shin, const float* __restrict__ ca)
{
  int part = blockIdx.x & 7, bh = blockIdx.x >> 3;
  int h = bh & 63, b = bh >> 6;
  int e0 = part * 1024 + threadIdx.x * 4;
  size_t base = (size_t)bh * 32 * 8192;
  float hc[4] = {0.f, 0.f, 0.f, 0.f};
  for (int c = 0; c < 32; c++) {
    float sc = expf(ca[(((size_t)(b * 32 + c)) * 64 + h) * 64 + 63]);
    size_t off = base + (size_t)c * 8192 + e0;
    uint2 sv = *(uint2*)&Shin[off];
    unsigned short* sp = (unsigned short*)&sv;
    unsigned short ho[4];
#pragma unroll
    for (int q = 0; q < 4; q++) ho[q] = f2bf(hc[q]);
    *(uint2*)&Shin[off] = *(uint2*)ho;
#pragma unroll
    for (int q = 0; q < 4; q++) hc[q] = sc * hc[q] + bf2f(sp[q]);
  }
}

// y[i,p] = sum_j M'[i,j]*x[j,p] + sum_n (C[i,n]e^ca_i)*hin[p,n] + Dskip*x[i,p]
// with dt folded into M' = G*exp(ca_i-ca_j)*dt_j. One K=192 MFMA per (b,h,c).
__global__ __launch_bounds__(256) void chunk_y_kernel(
    const unsigned short* __restrict__ G, const unsigned short* __restrict__ Cbf,
    const unsigned short* __restrict__ xconv, const float* __restrict__ dtv,
    const float* __restrict__ ca, const unsigned short* __restrict__ hin,
    const float* __restrict__ Dskip, unsigned short* __restrict__ yp)
{
  __shared__ __align__(16) unsigned short Aop[64][200];
  __shared__ __align__(16) unsigned short Bop[64][200];
  __shared__ float cas[64]; __shared__ float dts[64];
  int tid = threadIdx.x;
  int c = blockIdx.x & 31, h = (blockIdx.x >> 5) & 63, b = blockIdx.x >> 11;
  int cb = b * 32 + c;
  size_t bt0 = (size_t)cb * 64;
  if (tid < 64) {
    cas[tid] = ca[((size_t)cb * 64 + h) * 64 + tid];
    dts[tid] = dtv[(bt0 + tid) * 64 + h];
  }
  __syncthreads();
  {
    int i = tid >> 2, jseg = (tid & 3) * 16;
    float cai = cas[i];
    unsigned short gv[16];
    *(uint4*)&gv[0] = *(const uint4*)&G[(size_t)cb * 4096 + i * 64 + jseg];
    *(uint4*)&gv[8] = *(const uint4*)&G[(size_t)cb * 4096 + i * 64 + jseg + 8];
    unsigned short o[16];
#pragma unroll
    for (int q = 0; q < 16; q++) {
      int j = jseg + q;
      float m = (j <= i) ? bf2f(gv[q]) * expf(cai - cas[j]) * dts[j] : 0.f;
      o[q] = f2bf(m);
    }
    *(uint4*)&Aop[i][jseg] = *(uint4*)&o[0];
    *(uint4*)&Aop[i][jseg + 8] = *(uint4*)&o[8];
  }
  {
    int i = tid >> 2, nseg = (tid & 3) * 32;
    float sci = expf(cas[i]);
#pragma unroll
    for (int u = 0; u < 32; u += 8) {
      unsigned short cv[8];
      *(uint4*)cv = *(const uint4*)&Cbf[(bt0 + i) * 128 + nseg + u];
      unsigned short o[8];
#pragma unroll
      for (int q = 0; q < 8; q++) o[q] = f2bf(sci * bf2f(cv[q]));
      *(uint4*)&Aop[i][64 + nseg + u] = *(uint4*)o;
    }
  }
  {
    int j = tid >> 2, pseg = (tid & 3) * 16;
    unsigned short xv[16];
    *(uint4*)&xv[0] = *(const uint4*)&xconv[(bt0 + j) * 4096 + h * 64 + pseg];
    *(uint4*)&xv[8] = *(const uint4*)&xconv[(bt0 + j) * 4096 + h * 64 + pseg + 8];
#pragma unroll
    for (int q = 0; q < 16; q++) Bop[pseg + q][j] = xv[q];
  }
  {
    int p = tid >> 2, nseg = (tid & 3) * 32;
    size_t hb = ((size_t)(b * 64 + h) * 32 + c) * 8192 + p * 128 + nseg;
#pragma unroll
    for (int u = 0; u < 32; u += 8)
      *(uint4*)&Bop[p][64 + nseg + u] = *(const uint4*)&hin[hb + u];
  }
  __syncthreads();
  int wave = tid >> 6, lane = tid & 63, lm = lane & 15, kq = (lane >> 4) * 8, rq = lane >> 4;
  f32x4 acc[4] = {};
#pragma unroll
  for (int ks = 0; ks < 6; ks++) {
    bf16x8 af = *(const bf16x8*)&Aop[wave * 16 + lm][ks * 32 + kq];
#pragma unroll
    for (int pt = 0; pt < 4; pt++) {
      bf16x8 bb = *(const bf16x8*)&Bop[pt * 16 + lm][ks * 32 + kq];
      acc[pt] = __builtin_amdgcn_mfma_f32_16x16x32_bf16(af, bb, acc[pt], 0, 0, 0);
    }
  }
  float dsk = Dskip[h];
#pragma unroll
  for (int pt = 0; pt < 4; pt++)
#pragma unroll
    for (int r = 0; r < 4; r++) {
      int i = wave * 16 + rq * 4 + r, p = pt * 16 + lm;
      float y = acc[pt][r] + dsk * bf2f(Bop[p][i]);   // Bop[p][i] = x[i,p]
      yp[(bt0 + i) * 4096 + h * 64 + p] = f2bf(y);
    }
}

// gate with silu(z), rmsnorm, write bf16.
__global__ __launch_bounds__(256) void gate_norm_kernel(
    const unsigned short* __restrict__ yp, const unsigned short* __restrict__ zx,
    const float* __restrict__ norm_w, unsigned short* __restrict__ ybf)
{
  int row = blockIdx.x; int tid = threadIdx.x;
  int c0 = tid * 16;
  unsigned short y0[16], zv[16];
  const size_t base = (size_t)row * D_INNER + c0;
  *(uint4*)&y0[0] = *(const uint4*)&yp[base];
  *(uint4*)&y0[8] = *(const uint4*)&yp[base + 8];
  const size_t zbase = (size_t)row * D_IN_PROJ + c0;
  *(uint4*)&zv[0] = *(const uint4*)&zx[zbase];
  *(uint4*)&zv[8] = *(const uint4*)&zx[zbase + 8];

  float g[16]; float ss = 0.f;
#pragma unroll
  for (int i = 0; i < 16; i++) {
    float y = bf2f(y0[i]);
    float z = bf2f(zv[i]);
    float gate = z / (1.f + expf(-z));
    float gv = y * gate;
    g[i] = gv; ss += gv * gv;
  }
#pragma unroll
  for (int o = 32; o >= 1; o >>= 1) ss += __shfl_xor(ss, o);
  __shared__ float red[4]; __shared__ float stot;
  if ((tid & 63) == 0) red[tid >> 6] = ss;
  __syncthreads();
  if (tid == 0) stot = red[0] + red[1] + red[2] + red[3];
  __syncthreads();
  float scale = rsqrtf(stot * (1.f / D_INNER) + EPS_F);
  unsigned short o16[16];
#pragma unroll
  for (int i = 0; i < 16; i++) o16[i] = f2bf(g[i] * scale * norm_w[c0 + i]);
  *(uint4*)&ybf[base] = *(uint4*)&o16[0];
  *(uint4*)&ybf[base + 8] = *(uint4*)&o16[8];
}

extern "C" void kernel_launch(void* const* d_in, const int* in_sizes, int n_in,
                              void* d_out, int out_size, void* d_ws, size_t ws_size,
                              hipStream_t stream) {
  (void)in_sizes; (void)n_in; (void)out_size; (void)ws_size;
  const float* x          = (const float*)d_in[0];
  const float* in_proj_w  = (const float*)d_in[3];
  const float* conv_w     = (const float*)d_in[4];
  const float* conv_b     = (const float*)d_in[5];
  const float* dt_bias    = (const float*)d_in[6];
  const float* A_log      = (const float*)d_in[7];
  const float* Dskip      = (const float*)d_in[8];
  const float* norm_w     = (const float*)d_in[9];
  const float* out_proj_w = (const float*)d_in[10];
  float* out = (float*)d_out;

  char* w = (char*)d_ws;
  unsigned short* zx    = (unsigned short*)(w);
  unsigned short* xconv = (unsigned short*)(w + 69730304);
  unsigned short* Bbf = (unsigned short*)(w + 103284736);   // BT*128 bf16
  unsigned short* Cbf = (unsigned short*)(w + 105381888);   // BT*128 bf16
  float* dtv = (float*)(w + 107479040);
  float* ca  = (float*)(w + 109576192);
  unsigned short* G    = (unsigned short*)(w + 110624768);
  unsigned short* Shin = (unsigned short*)(w + 111149056);
  unsigned short* yp   = (unsigned short*)(w + 178257920);
  unsigned short* xb   = (unsigned short*)(w + 111149056);   // pre-scan overlay
  unsigned short* wib  = (unsigned short*)(w + 127926272);   // pre-scan overlay (padded to 8704 rows)
  unsigned short* ybf  = (unsigned short*)(w + 111149056);   // post-scan overlay
  unsigned short* wob  = (unsigned short*)(w + 144703488);   // post-scan overlay

  cast_kernel<<<BT * D_MODEL / 8 / 256, 256, 0, stream>>>(x, xb, BT * D_MODEL);
  cast_kernel<<<D_IN_PROJ * D_MODEL / 8 / 256, 256, 0, stream>>>(in_proj_w, wib, D_IN_PROJ * D_MODEL);
  {
    // 256^2 deep-pipelined GEMM; N padded to 34 tiles (8704). Rows 8512..8703
    // of wib are garbage: they feed only accumulator columns >= N (store-guarded).
    int NT = 34, MT = BT / 256;
    gemm256_kernel<false><<<NT * MT, 512, 0, stream>>>(
        xb, wib, zx, BT, D_IN_PROJ, D_MODEL, NT, MT);
  }
  conv_silu_kernel<<<(BT * (CONV_DIM / 8) + 255) / 256, 256, 0, stream>>>(
      zx, conv_w, conv_b, xconv, Bbf, Cbf);
  dtcum_kernel<<<BB * NCHUNK * NHEADS / 4, 256, 0, stream>>>(zx, dt_bias, A_log, dtv, ca);
  chunk_g_kernel<<<BB * NCHUNK, 256, 0, stream>>>(Bbf, Cbf, G);
  chunk_state_kernel<<<BB * 16 * NCHUNK, 256, 0, stream>>>(Bbf, xconv, dtv, ca, Shin);
  state_pass_kernel<<<BB * NHEADS * 8, 256, 0, stream>>>(Shin, ca);
  chunk_y_kernel<<<BB * NHEADS * NCHUNK, 256, 0, stream>>>(G, Cbf, xconv, dtv, ca, Shin, Dskip, yp);
  gate_norm_kernel<<<BT, 256, 0, stream>>>(yp, zx, norm_w, ybf);
  cast_kernel<<<D_MODEL * D_INNER / 8 / 256, 256, 0, stream>>>(out_proj_w, wob, D_MODEL * D_INNER);
  {
    int NT = D_MODEL / 128, MT = BT / 128;
    gemm_tn_kernel<true><<<NT * MT, 256, 0, stream>>>(
        ybf, wob, out, BT, D_MODEL, D_INNER, NT, MT);
  }
}